// Round 10
// baseline (183.079 us; speedup 1.0000x reference)
//
#include <hip/hip_runtime.h>

#define NTOK 2048
#define CDIM 1024
#define NHEAD 16
#define HDIM 64
#define NFRM 8
#define FTOK 256

typedef unsigned short ushort;
typedef unsigned long long u64;
typedef __attribute__((ext_vector_type(8))) short short8;     // 8 bf16 = 4 VGPRs (MFMA A/B frag)
typedef __attribute__((ext_vector_type(8))) ushort ushort8;
typedef __attribute__((ext_vector_type(4))) ushort ushort4v;
typedef __attribute__((ext_vector_type(4))) float floatx4;    // MFMA C/D frag

__device__ __forceinline__ ushort f2bf(float f) {
    unsigned int u = __float_as_uint(f);
    return (ushort)((u + 0x7fffu + ((u >> 16) & 1u)) >> 16);   // RNE
}

// async global->LDS, 16B per lane; LDS dest = wave-uniform base + lane*16
__device__ __forceinline__ void gload_lds16(const void* g, void* l) {
    __builtin_amdgcn_global_load_lds(
        (const __attribute__((address_space(1))) unsigned int*)(uintptr_t)g,
        (__attribute__((address_space(3))) unsigned int*)(unsigned int)(uintptr_t)l,
        16, 0, 0);
}

// ---------------------------------------------------------------------------
// Fused prep: [0,2048) x fp32->bf16 ; [2048,2816) Wqkv^T ; [2816,3072) Wproj^T
// [3072] hub bitmask
// ---------------------------------------------------------------------------
__global__ __launch_bounds__(256)
void prep_kernel(const float* __restrict__ x, ushort* __restrict__ xb,
                 const float* __restrict__ Wqkv, ushort* __restrict__ wqkvT,
                 const float* __restrict__ Wproj, ushort* __restrict__ wprojT,
                 const int* __restrict__ is_hub, u64* __restrict__ hubmask)
{
    __shared__ ushort LT[64][72];   // [n][k]
    const int b = blockIdx.x, t = threadIdx.x;

    if (b < 2048) {                 // convx: 2048 blocks x 256 float4
        int i = b * 256 + t;
        float4 f = ((const float4*)x)[i];
        ushort4v o = { f2bf(f.x), f2bf(f.y), f2bf(f.z), f2bf(f.w) };
        ((ushort4v*)xb)[i] = o;
        return;
    }
    if (b >= 3072) {                // hub bitmask: 32 tiles of 64 tokens
        if (t < NTOK / 64) {
            u64 m = 0;
            for (int j = 0; j < 64; ++j)
                m |= (u64)(is_hub[t * 64 + j] != 0) << j;
            hubmask[t] = m;
        }
        return;
    }

    const float* W; ushort* WT; int K, N, n0, k0;
    if (b < 2816) { int idx = b - 2048; W = Wqkv;  WT = wqkvT;  K = 1024; N = 3072;
                    n0 = (idx % 48) * 64; k0 = (idx / 48) * 64; }
    else          { int idx = b - 2816; W = Wproj; WT = wprojT; K = 1024; N = 1024;
                    n0 = (idx & 15) * 64; k0 = (idx >> 4) * 64; }

    const int kr = t >> 4, nc = t & 15;
#pragma unroll
    for (int i = 0; i < 4; ++i) {
        int k = kr + i * 16;
        float4 w4 = *(const float4*)(W + (size_t)(k0 + k) * N + n0 + nc * 4);
        LT[nc*4+0][k] = f2bf(w4.x);
        LT[nc*4+1][k] = f2bf(w4.y);
        LT[nc*4+2][k] = f2bf(w4.z);
        LT[nc*4+3][k] = f2bf(w4.w);
    }
    __syncthreads();
    const int n = t >> 2;
#pragma unroll
    for (int half = 0; half < 2; ++half) {
        int kc = (t & 3) + 4 * half;
        ushort8 v = *(const ushort8*)&LT[n][kc * 8];
        *(ushort8*)(WT + (size_t)(n0 + n) * K + k0 + kc * 8) = v;
    }
}

// ---------------------------------------------------------------------------
// bf16 MFMA GEMM: C = A[M,K] @ BT[N,K]^T + bias
// mode 0: fp32 store row-major [M][N]
// mode 1: QKV scatter — Q,K parts -> qkvb [2][H][N][D]; V part -> vTb [H][D][N]
//         (V transposed in-epilogue: kills the separate vtrans kernel)
// ---------------------------------------------------------------------------
__global__ __launch_bounds__(256)
void gemm_bt_kernel(const ushort* __restrict__ A, const ushort* __restrict__ BT,
                    const float* __restrict__ bias, void* __restrict__ out,
                    ushort* __restrict__ vtb,
                    int M, int N, int K, int mode)
{
    __shared__ ushort As[2][128 * 32];
    __shared__ ushort Bs[2][128 * 32];

    const int t = threadIdx.x;
    const int wave = t >> 6, lane = t & 63;
    const int quad = lane >> 4, l15 = lane & 15;
    const int row0 = blockIdx.y * 128, col0 = blockIdx.x * 128;
    const int wm = (wave >> 1) * 64, wn = (wave & 1) * 64;

    const int sr = lane >> 2;         // row within a 16-row staging group
    const int sc = (lane & 3) * 8;    // ushort offset (16B chunks)
    const int r0 = wave * 32;

    floatx4 acc[4][4];
#pragma unroll
    for (int i = 0; i < 4; ++i)
#pragma unroll
        for (int j = 0; j < 4; ++j) acc[i][j] = (floatx4){0.f, 0.f, 0.f, 0.f};

    gload_lds16(A  + (size_t)(row0 + r0      + sr) * K + sc, &As[0][ r0       * 32]);
    gload_lds16(A  + (size_t)(row0 + r0 + 16 + sr) * K + sc, &As[0][(r0 + 16) * 32]);
    gload_lds16(BT + (size_t)(col0 + r0      + sr) * K + sc, &Bs[0][ r0       * 32]);
    gload_lds16(BT + (size_t)(col0 + r0 + 16 + sr) * K + sc, &Bs[0][(r0 + 16) * 32]);

    const int nk = K >> 5;
    for (int ki = 0; ki < nk; ++ki) {
        __syncthreads();   // buf[ki&1] staged; all waves done reading buf[(ki+1)&1]
        if (ki + 1 < nk) {
            const int kn = (ki + 1) << 5;
            const int b = (ki + 1) & 1;
            gload_lds16(A  + (size_t)(row0 + r0      + sr) * K + kn + sc, &As[b][ r0       * 32]);
            gload_lds16(A  + (size_t)(row0 + r0 + 16 + sr) * K + kn + sc, &As[b][(r0 + 16) * 32]);
            gload_lds16(BT + (size_t)(col0 + r0      + sr) * K + kn + sc, &Bs[b][ r0       * 32]);
            gload_lds16(BT + (size_t)(col0 + r0 + 16 + sr) * K + kn + sc, &Bs[b][(r0 + 16) * 32]);
        }
        const ushort* as = As[ki & 1];
        const ushort* bs = Bs[ki & 1];

        short8 af[4], bfr[4];
#pragma unroll
        for (int i = 0; i < 4; ++i)
            af[i] = *(const short8*)&as[(wm + i * 16 + l15) * 32 + quad * 8];
#pragma unroll
        for (int j = 0; j < 4; ++j)
            bfr[j] = *(const short8*)&bs[(wn + j * 16 + l15) * 32 + quad * 8];
#pragma unroll
        for (int i = 0; i < 4; ++i)
#pragma unroll
            for (int j = 0; j < 4; ++j)
                acc[i][j] = __builtin_amdgcn_mfma_f32_16x16x32_bf16(af[i], bfr[j], acc[i][j], 0, 0, 0);
    }

    if (mode == 0) {
        float* outf = (float*)out;
#pragma unroll
        for (int j = 0; j < 4; ++j) {
            int col = col0 + wn + j * 16 + l15;
            float bb = bias[col];
#pragma unroll
            for (int i = 0; i < 4; ++i) {
                int rowb = row0 + wm + i * 16 + quad * 4;
#pragma unroll
                for (int r = 0; r < 4; ++r)
                    outf[(size_t)(rowb + r) * N + col] = acc[i][j][r] + bb;
            }
        }
    } else {
        ushort* outb = (ushort*)out;
#pragma unroll
        for (int j = 0; j < 4; ++j) {
            int col = col0 + wn + j * 16 + l15;
            float bb = bias[col];
            int part = col >> 10, hh = (col >> 6) & 15, d = col & 63;
            if (part < 2) {        // Q,K -> [part][H][N][D]  (uniform branch per j)
                ushort* dst = outb + ((size_t)(part * NHEAD + hh) * NTOK) * HDIM + d;
#pragma unroll
                for (int i = 0; i < 4; ++i) {
                    int rowb = row0 + wm + i * 16 + quad * 4;
#pragma unroll
                    for (int r = 0; r < 4; ++r)
                        dst[(size_t)(rowb + r) * HDIM] = f2bf(acc[i][j][r] + bb);
                }
            } else {               // V -> vT [H][D][N] directly (fused transpose)
                ushort* dst = vtb + ((size_t)hh * HDIM + d) * NTOK;
#pragma unroll
                for (int i = 0; i < 4; ++i) {
                    int rowb = row0 + wm + i * 16 + quad * 4;
#pragma unroll
                    for (int r = 0; r < 4; ++r)
                        dst[rowb + r] = f2bf(acc[i][j][r] + bb);
                }
            }
        }
    }
}

// ---------------------------------------------------------------------------
// Single-wave MFMA flash attention, 128-key batched iterations.
// Per-wave serial exposures halved vs R8 (11 -> 5.5): each iteration does
// 2 k-tiles (QK 16 MFMA, one exp pass, PV 16 MFMA) against one prefetched
// K block. K register-double-buffered with STATIC buffer names (R6 lesson).
// No-max softmax (R8-validated): exp accumulated directly, one lane-reduce
// at the end. XCD-locked heads (b&15) keep K/V L2-resident (R6-R9).
// ---------------------------------------------------------------------------
__global__ __launch_bounds__(64)
void attn_wave_kernel(const ushort* __restrict__ qkvb,   // [2][H][N][D] bf16 (Q,K)
                      const ushort* __restrict__ vTb,    // [H][D][N] bf16
                      const int* __restrict__ frame_ids,
                      const u64* __restrict__ hubmask,   // [NTOK/64]
                      const int* __restrict__ adj,
                      const float* __restrict__ frame_bias,
                      ushort* __restrict__ attnb)        // [N][C] bf16
{
    __shared__ ushort Ps[16 * 144];   // 2 P strips side by side, row stride 144

    const int lane = threadIdx.x;
    const int quad = lane >> 4, l15 = lane & 15;
    const int b = blockIdx.x;
    const int h = b & 15, q0 = (b >> 4) * 16;   // XCD-locking swizzle

    const ushort* Qg = qkvb + ((size_t)h * NTOK) * HDIM;
    const ushort* Kg = qkvb + ((size_t)(NHEAD + h) * NTOK) * HDIM;
    const ushort* Vg = vTb + ((size_t)h * HDIM) * NTOK;

    // Q A-frags: A[m=l15][k=quad*8+j]
    short8 aq0 = *(const short8*)(Qg + (size_t)(q0 + l15) * HDIM + quad * 8);
    short8 aq1 = *(const short8*)(Qg + (size_t)(q0 + l15) * HDIM + 32 + quad * 8);

    // packed visible-frame list (uniform)
    const int fq = frame_ids[q0];
    unsigned vpack = 0; int nv = 0;
#pragma unroll
    for (int f = 0; f < NFRM; ++f)
        if (adj[fq * NFRM + f]) { vpack |= (unsigned)f << (3 * nv); ++nv; }
    const int ntot2 = nv * 2;         // 128-key iterations; even

    const u64 hmq = hubmask[q0 >> 6] >> (q0 & 63);
    int qh[4];
#pragma unroll
    for (int r = 0; r < 4; ++r) qh[r] = (int)((hmq >> (quad * 4 + r)) & 1);

    float lpart[4] = {0.f, 0.f, 0.f, 0.f};
    floatx4 oacc[4];
#pragma unroll
    for (int dt = 0; dt < 4; ++dt) oacc[dt] = (floatx4){0.f, 0.f, 0.f, 0.f};

    auto blk_k0 = [&](int it) -> int {
        const int fj = (int)((vpack >> (3 * (it >> 1))) & 7u);
        return fj * FTOK + (it & 1) * 128;
    };

    // load one 128-key K block (2 tiles x 4 nt x 2 frags = 16 short8)
    auto load_k = [&](int k0, short8 (&ka)[2][4], short8 (&kb)[2][4]) {
#pragma unroll
        for (int tt = 0; tt < 2; ++tt)
#pragma unroll
            for (int nt = 0; nt < 4; ++nt) {
                const ushort* kp = Kg + (size_t)(k0 + tt * 64 + nt * 16 + l15) * HDIM;
                ka[tt][nt] = *(const short8*)(kp + quad * 8);
                kb[tt][nt] = *(const short8*)(kp + 32 + quad * 8);
            }
    };

    auto do_iter = [&](int it,
                       short8 (&kaC)[2][4], short8 (&kbC)[2][4],
                       short8 (&kaN)[2][4], short8 (&kbN)[2][4]) {
        const int fj = (int)((vpack >> (3 * (it >> 1))) & 7u);
        const int k0 = fj * FTOK + (it & 1) * 128;
        const float fb = frame_bias[fq * NFRM + fj];
        const bool same = (fj == fq);
        const u64 hm0 = hubmask[k0 >> 6];
        const u64 hm1 = hubmask[(k0 >> 6) + 1];

        // S = Q @ K^T for both tiles (K frags resident)
        floatx4 s[2][4];
#pragma unroll
        for (int tt = 0; tt < 2; ++tt)
#pragma unroll
            for (int nt = 0; nt < 4; ++nt) {
                s[tt][nt] = (floatx4){0.f, 0.f, 0.f, 0.f};
                s[tt][nt] = __builtin_amdgcn_mfma_f32_16x16x32_bf16(aq0, kaC[tt][nt], s[tt][nt], 0, 0, 0);
                s[tt][nt] = __builtin_amdgcn_mfma_f32_16x16x32_bf16(aq1, kbC[tt][nt], s[tt][nt], 0, 0, 0);
            }

        // prefetch next 128-key block (lands during exp/PV)
        if (it + 1 < ntot2) load_k(blk_k0(it + 1), kaN, kbN);

        // mask + scale + bias + exp (no max, no cross-lane); P -> LDS strips
#pragma unroll
        for (int r = 0; r < 4; ++r) {
            float ps = 0.f;
#pragma unroll
            for (int tt = 0; tt < 2; ++tt) {
                const u64 hm = tt ? hm1 : hm0;
#pragma unroll
                for (int nt = 0; nt < 4; ++nt) {
                    int kh = (int)((hm >> (nt * 16 + l15)) & 1);
                    bool allow = same || ((qh[r] == 0) && (kh == 0));
                    float sv = allow ? fmaf(s[tt][nt][r], 0.125f, fb) : -1.0e30f;
                    float p = __expf(sv);          // exp(-1e30) = 0 exactly
                    ps += p;
                    Ps[(quad * 4 + r) * 144 + tt * 72 + nt * 16 + l15] = f2bf(p);
                }
            }
            lpart[r] += ps;
        }

        // O += P @ V for both tiles (V loaded here, just before use)
#pragma unroll
        for (int tt = 0; tt < 2; ++tt) {
            short8 ap0 = *(const short8*)&Ps[l15 * 144 + tt * 72 + quad * 8];
            short8 ap1 = *(const short8*)&Ps[l15 * 144 + tt * 72 + 32 + quad * 8];
#pragma unroll
            for (int dt = 0; dt < 4; ++dt) {
                const ushort* vp = Vg + (size_t)(dt * 16 + l15) * NTOK + k0 + tt * 64;
                short8 bv0 = *(const short8*)(vp + quad * 8);
                short8 bv1 = *(const short8*)(vp + 32 + quad * 8);
                oacc[dt] = __builtin_amdgcn_mfma_f32_16x16x32_bf16(ap0, bv0, oacc[dt], 0, 0, 0);
                oacc[dt] = __builtin_amdgcn_mfma_f32_16x16x32_bf16(ap1, bv1, oacc[dt], 0, 0, 0);
            }
        }
    };

    // static K double buffer; ntot2 even -> clean 2x unroll
    short8 kaA[2][4], kbA[2][4], kaB[2][4], kbB[2][4];
    load_k(blk_k0(0), kaA, kbA);

    for (int it = 0; it < ntot2; it += 2) {
        do_iter(it,     kaA, kbA, kaB, kbB);
        do_iter(it + 1, kaB, kbB, kaA, kbA);
    }

    // final row-sum reduction across the 16 l15 lanes (once per kernel)
    float linv[4];
#pragma unroll
    for (int r = 0; r < 4; ++r) {
        float ls = lpart[r];
        ls += __shfl_xor(ls, 1);
        ls += __shfl_xor(ls, 2);
        ls += __shfl_xor(ls, 4);
        ls += __shfl_xor(ls, 8);
        linv[r] = 1.0f / ls;
    }

    // epilogue: attnb[row][h*64 + d] bf16
#pragma unroll
    for (int dt = 0; dt < 4; ++dt) {
        int col = h * HDIM + dt * 16 + l15;
#pragma unroll
        for (int r = 0; r < 4; ++r) {
            int row = q0 + quad * 4 + r;
            attnb[(size_t)row * CDIM + col] = f2bf(oacc[dt][r] * linv[r]);
        }
    }
}

// ---------------------------------------------------------------------------
extern "C" void kernel_launch(void* const* d_in, const int* in_sizes, int n_in,
                              void* d_out, int out_size, void* d_ws, size_t ws_size,
                              hipStream_t stream)
{
    const float* x          = (const float*)d_in[0];
    const int*   frame_ids  = (const int*)d_in[1];
    const int*   is_hub     = (const int*)d_in[2];
    const int*   adj        = (const int*)d_in[3];
    const float* frame_bias = (const float*)d_in[4];
    const float* Wqkv       = (const float*)d_in[5];
    const float* bqkv       = (const float*)d_in[6];
    const float* Wproj      = (const float*)d_in[7];
    const float* bproj      = (const float*)d_in[8];
    float* out = (float*)d_out;

    // workspace layout (ushort units) — same offsets as R9
    ushort* xb     = (ushort*)d_ws;            // 2048*1024
    ushort* wqkvT  = xb     + 2097152;         // 3072*1024
    ushort* wprojT = wqkvT  + 3145728;         // 1024*1024
    ushort* qkvb   = wprojT + 1048576;         // [2][H][N][D] used (V slot unused)
    ushort* vTb    = qkvb   + 6291456;         // 16*64*2048
    ushort* attnb  = vTb    + 2097152;         // 2048*1024
    u64*    hubmask = (u64*)(attnb + 2097152); // 32 x u64

    prep_kernel<<<dim3(3073), dim3(256), 0, stream>>>(
        x, xb, Wqkv, wqkvT, Wproj, wprojT, is_hub, hubmask);

    // QKV: [2048,1024] @ [1024,3072]; Q,K -> qkvb, V -> vTb (fused transpose)
    gemm_bt_kernel<<<dim3(3 * CDIM / 128, NTOK / 128), dim3(256), 0, stream>>>(
        xb, wqkvT, bqkv, qkvb, vTb, NTOK, 3 * CDIM, CDIM, 1);

    attn_wave_kernel<<<dim3(2048), dim3(64), 0, stream>>>(
        qkvb, vTb, frame_ids, hubmask, adj, frame_bias, attnb);

    // proj: [2048,1024] @ [1024,1024] -> fp32 d_out
    gemm_bt_kernel<<<dim3(CDIM / 128, NTOK / 128), dim3(256), 0, stream>>>(
        attnb, wprojT, bproj, out, nullptr, NTOK, CDIM, CDIM, 0);
}

// Round 11
// 154.300 us; speedup vs baseline: 1.1865x; 1.1865x over previous
//
#include <hip/hip_runtime.h>

#define NTOK 2048
#define CDIM 1024
#define NHEAD 16
#define HDIM 64
#define NFRM 8
#define FTOK 256

typedef unsigned short ushort;
typedef unsigned long long u64;
typedef __attribute__((ext_vector_type(8))) short short8;     // 8 bf16 = 4 VGPRs (MFMA A/B frag)
typedef __attribute__((ext_vector_type(8))) ushort ushort8;
typedef __attribute__((ext_vector_type(4))) ushort ushort4v;
typedef __attribute__((ext_vector_type(4))) float floatx4;    // MFMA C/D frag

__device__ __forceinline__ ushort f2bf(float f) {
    unsigned int u = __float_as_uint(f);
    return (ushort)((u + 0x7fffu + ((u >> 16) & 1u)) >> 16);   // RNE
}

// async global->LDS, 16B per lane; LDS dest = wave-uniform base + lane*16
__device__ __forceinline__ void gload_lds16(const void* g, void* l) {
    __builtin_amdgcn_global_load_lds(
        (const __attribute__((address_space(1))) unsigned int*)(uintptr_t)g,
        (__attribute__((address_space(3))) unsigned int*)(unsigned int)(uintptr_t)l,
        16, 0, 0);
}

// ---------------------------------------------------------------------------
// Fused prep: [0,2048) x fp32->bf16 ; [2048,2816) Wqkv^T ; [2816,3072) Wproj^T
// [3072] hub bitmask
// ---------------------------------------------------------------------------
__global__ __launch_bounds__(256)
void prep_kernel(const float* __restrict__ x, ushort* __restrict__ xb,
                 const float* __restrict__ Wqkv, ushort* __restrict__ wqkvT,
                 const float* __restrict__ Wproj, ushort* __restrict__ wprojT,
                 const int* __restrict__ is_hub, u64* __restrict__ hubmask)
{
    __shared__ ushort LT[64][72];   // [n][k]
    const int b = blockIdx.x, t = threadIdx.x;

    if (b < 2048) {                 // convx: 2048 blocks x 256 float4
        int i = b * 256 + t;
        float4 f = ((const float4*)x)[i];
        ushort4v o = { f2bf(f.x), f2bf(f.y), f2bf(f.z), f2bf(f.w) };
        ((ushort4v*)xb)[i] = o;
        return;
    }
    if (b >= 3072) {                // hub bitmask: 32 tiles of 64 tokens
        if (t < NTOK / 64) {
            u64 m = 0;
            for (int j = 0; j < 64; ++j)
                m |= (u64)(is_hub[t * 64 + j] != 0) << j;
            hubmask[t] = m;
        }
        return;
    }

    const float* W; ushort* WT; int K, N, n0, k0;
    if (b < 2816) { int idx = b - 2048; W = Wqkv;  WT = wqkvT;  K = 1024; N = 3072;
                    n0 = (idx % 48) * 64; k0 = (idx / 48) * 64; }
    else          { int idx = b - 2816; W = Wproj; WT = wprojT; K = 1024; N = 1024;
                    n0 = (idx & 15) * 64; k0 = (idx >> 4) * 64; }

    const int kr = t >> 4, nc = t & 15;
#pragma unroll
    for (int i = 0; i < 4; ++i) {
        int k = kr + i * 16;
        float4 w4 = *(const float4*)(W + (size_t)(k0 + k) * N + n0 + nc * 4);
        LT[nc*4+0][k] = f2bf(w4.x);
        LT[nc*4+1][k] = f2bf(w4.y);
        LT[nc*4+2][k] = f2bf(w4.z);
        LT[nc*4+3][k] = f2bf(w4.w);
    }
    __syncthreads();
    const int n = t >> 2;
#pragma unroll
    for (int half = 0; half < 2; ++half) {
        int kc = (t & 3) + 4 * half;
        ushort8 v = *(const ushort8*)&LT[n][kc * 8];
        *(ushort8*)(WT + (size_t)(n0 + n) * K + k0 + kc * 8) = v;
    }
}

// ---------------------------------------------------------------------------
// bf16 MFMA GEMM: C = A[M,K] @ BT[N,K]^T + bias
// mode 0: fp32 store row-major [M][N]
// mode 1: QKV scatter — Q,K -> qkvb [2][H][N][D]; V -> vTb [H][D][N] (fused T)
// ---------------------------------------------------------------------------
__global__ __launch_bounds__(256)
void gemm_bt_kernel(const ushort* __restrict__ A, const ushort* __restrict__ BT,
                    const float* __restrict__ bias, void* __restrict__ out,
                    ushort* __restrict__ vtb,
                    int M, int N, int K, int mode)
{
    __shared__ ushort As[2][128 * 32];
    __shared__ ushort Bs[2][128 * 32];

    const int t = threadIdx.x;
    const int wave = t >> 6, lane = t & 63;
    const int quad = lane >> 4, l15 = lane & 15;
    const int row0 = blockIdx.y * 128, col0 = blockIdx.x * 128;
    const int wm = (wave >> 1) * 64, wn = (wave & 1) * 64;

    const int sr = lane >> 2;         // row within a 16-row staging group
    const int sc = (lane & 3) * 8;    // ushort offset (16B chunks)
    const int r0 = wave * 32;

    floatx4 acc[4][4];
#pragma unroll
    for (int i = 0; i < 4; ++i)
#pragma unroll
        for (int j = 0; j < 4; ++j) acc[i][j] = (floatx4){0.f, 0.f, 0.f, 0.f};

    gload_lds16(A  + (size_t)(row0 + r0      + sr) * K + sc, &As[0][ r0       * 32]);
    gload_lds16(A  + (size_t)(row0 + r0 + 16 + sr) * K + sc, &As[0][(r0 + 16) * 32]);
    gload_lds16(BT + (size_t)(col0 + r0      + sr) * K + sc, &Bs[0][ r0       * 32]);
    gload_lds16(BT + (size_t)(col0 + r0 + 16 + sr) * K + sc, &Bs[0][(r0 + 16) * 32]);

    const int nk = K >> 5;
    for (int ki = 0; ki < nk; ++ki) {
        __syncthreads();   // buf[ki&1] staged; all waves done reading buf[(ki+1)&1]
        if (ki + 1 < nk) {
            const int kn = (ki + 1) << 5;
            const int b = (ki + 1) & 1;
            gload_lds16(A  + (size_t)(row0 + r0      + sr) * K + kn + sc, &As[b][ r0       * 32]);
            gload_lds16(A  + (size_t)(row0 + r0 + 16 + sr) * K + kn + sc, &As[b][(r0 + 16) * 32]);
            gload_lds16(BT + (size_t)(col0 + r0      + sr) * K + kn + sc, &Bs[b][ r0       * 32]);
            gload_lds16(BT + (size_t)(col0 + r0 + 16 + sr) * K + kn + sc, &Bs[b][(r0 + 16) * 32]);
        }
        const ushort* as = As[ki & 1];
        const ushort* bs = Bs[ki & 1];

        short8 af[4], bfr[4];
#pragma unroll
        for (int i = 0; i < 4; ++i)
            af[i] = *(const short8*)&as[(wm + i * 16 + l15) * 32 + quad * 8];
#pragma unroll
        for (int j = 0; j < 4; ++j)
            bfr[j] = *(const short8*)&bs[(wn + j * 16 + l15) * 32 + quad * 8];
#pragma unroll
        for (int i = 0; i < 4; ++i)
#pragma unroll
            for (int j = 0; j < 4; ++j)
                acc[i][j] = __builtin_amdgcn_mfma_f32_16x16x32_bf16(af[i], bfr[j], acc[i][j], 0, 0, 0);
    }

    if (mode == 0) {
        float* outf = (float*)out;
#pragma unroll
        for (int j = 0; j < 4; ++j) {
            int col = col0 + wn + j * 16 + l15;
            float bb = bias[col];
#pragma unroll
            for (int i = 0; i < 4; ++i) {
                int rowb = row0 + wm + i * 16 + quad * 4;
#pragma unroll
                for (int r = 0; r < 4; ++r)
                    outf[(size_t)(rowb + r) * N + col] = acc[i][j][r] + bb;
            }
        }
    } else {
        ushort* outb = (ushort*)out;
#pragma unroll
        for (int j = 0; j < 4; ++j) {
            int col = col0 + wn + j * 16 + l15;
            float bb = bias[col];
            int part = col >> 10, hh = (col >> 6) & 15, d = col & 63;
            if (part < 2) {        // Q,K -> [part][H][N][D]
                ushort* dst = outb + ((size_t)(part * NHEAD + hh) * NTOK) * HDIM + d;
#pragma unroll
                for (int i = 0; i < 4; ++i) {
                    int rowb = row0 + wm + i * 16 + quad * 4;
#pragma unroll
                    for (int r = 0; r < 4; ++r)
                        dst[(size_t)(rowb + r) * HDIM] = f2bf(acc[i][j][r] + bb);
                }
            } else {               // V -> vT [H][D][N] directly (fused transpose)
                ushort* dst = vtb + ((size_t)hh * HDIM + d) * NTOK;
#pragma unroll
                for (int i = 0; i < 4; ++i) {
                    int rowb = row0 + wm + i * 16 + quad * 4;
#pragma unroll
                    for (int r = 0; r < 4; ++r)
                        dst[rowb + r] = f2bf(acc[i][j][r] + bb);
                }
            }
        }
    }
}

// ---------------------------------------------------------------------------
// Staged MFMA flash attention: block = (head, 64-q tile), 4 waves.
// K/V tiles staged to LDS with COALESCED 1KB/instr loads (4x fewer memory
// instructions per unit work than the R8 register-gather), rows padded to
// 72 ushorts -> 2-way max bank conflicts (R3/R4 had 16-way at stride 64).
// Double-buffered staging, one barrier per tile (prefetch flies a full
// compute phase). No-max softmax (R8), XCD-locked heads (R6), hubmask (R9).
// ---------------------------------------------------------------------------
__global__ __launch_bounds__(256)
void attn_tile_kernel(const ushort* __restrict__ qkvb,   // [2][H][N][D] bf16 (Q,K)
                      const ushort* __restrict__ vTb,    // [H][D][N] bf16
                      const int* __restrict__ frame_ids,
                      const u64* __restrict__ hubmask,   // [NTOK/64]
                      const int* __restrict__ adj,
                      const float* __restrict__ frame_bias,
                      ushort* __restrict__ attnb)        // [N][C] bf16
{
    __shared__ ushort Ks [2][64 * 72];   // K  tile [key][d], padded
    __shared__ ushort VTs[2][64 * 72];   // V^T tile [d][key], padded
    __shared__ ushort Ps [4][16 * 72];   // per-wave P strip

    const int t = threadIdx.x;
    const int wave = t >> 6, lane = t & 63;
    const int quad = lane >> 4, l15 = lane & 15;
    const int b = blockIdx.x;
    const int h = b & 15, q0 = (b >> 4) * 64;   // XCD-locking swizzle

    const ushort* Qg = qkvb + ((size_t)h * NTOK) * HDIM;
    const ushort* Kg = qkvb + ((size_t)(NHEAD + h) * NTOK) * HDIM;
    const ushort* Vg = vTb + ((size_t)h * HDIM) * NTOK;

    // Q A-frags in registers (wave owns q rows q0+wave*16 .. +16)
    short8 aq0 = *(const short8*)(Qg + (size_t)(q0 + wave * 16 + l15) * HDIM + quad * 8);
    short8 aq1 = *(const short8*)(Qg + (size_t)(q0 + wave * 16 + l15) * HDIM + 32 + quad * 8);

    // packed visible-frame list (uniform)
    const int fq = frame_ids[q0];
    unsigned vpack = 0; int nv = 0;
#pragma unroll
    for (int f = 0; f < NFRM; ++f)
        if (adj[fq * NFRM + f]) { vpack |= (unsigned)f << (3 * nv); ++nv; }
    const int ntot = nv * 4;

    const u64 hmq = hubmask[q0 >> 6];
    int qh[4];
#pragma unroll
    for (int r = 0; r < 4; ++r) qh[r] = (int)((hmq >> (wave * 16 + quad * 4 + r)) & 1);

    float lpart[4] = {0.f, 0.f, 0.f, 0.f};
    floatx4 oacc[4];
#pragma unroll
    for (int dt = 0; dt < 4; ++dt) oacc[dt] = (floatx4){0.f, 0.f, 0.f, 0.f};

    // staging mapping: wave stages rows [wave*16, wave*16+16); lane covers
    // row wave*16 + (lane>>3) (+8), 16B chunk (lane&7) -> 1KB contiguous/instr
    const int sro = wave * 16 + (lane >> 3);
    const int sc  = (lane & 7) * 8;

    auto tile_k0 = [&](int vt) -> int {
        const int fj = (int)((vpack >> (3 * (vt >> 2))) & 7u);
        return fj * FTOK + (vt & 3) * 64;
    };

    auto stage = [&](int vt) {
        const int k0 = tile_k0(vt);
        const int bf = vt & 1;
        ushort8 k8a = *(const ushort8*)(Kg + (size_t)(k0 + sro)     * HDIM + sc);
        ushort8 k8b = *(const ushort8*)(Kg + (size_t)(k0 + sro + 8) * HDIM + sc);
        ushort8 v8a = *(const ushort8*)(Vg + (size_t)(sro)     * NTOK + k0 + sc);
        ushort8 v8b = *(const ushort8*)(Vg + (size_t)(sro + 8) * NTOK + k0 + sc);
        *(ushort8*)&Ks [bf][ sro      * 72 + sc] = k8a;
        *(ushort8*)&Ks [bf][(sro + 8) * 72 + sc] = k8b;
        *(ushort8*)&VTs[bf][ sro      * 72 + sc] = v8a;
        *(ushort8*)&VTs[bf][(sro + 8) * 72 + sc] = v8b;
    };

    stage(0);

    for (int vt = 0; vt < ntot; ++vt) {
        __syncthreads();   // buf[vt&1] staged; buf[(vt+1)&1] free (read 2 iters ago)

        if (vt + 1 < ntot) stage(vt + 1);   // prefetch flies across this compute

        const int fj = (int)((vpack >> (3 * (vt >> 2))) & 7u);
        const int k0 = fj * FTOK + (vt & 3) * 64;
        const float fb = frame_bias[fq * NFRM + fj];
        const bool same = (fj == fq);
        const u64 hmk = hubmask[k0 >> 6];
        const ushort* ks = Ks[vt & 1];
        const ushort* vs = VTs[vt & 1];

        // S strip [16 q][64 keys] = Q @ K^T (padded LDS, 2-way max conflicts)
        floatx4 s[4];
#pragma unroll
        for (int nt = 0; nt < 4; ++nt) {
            short8 bk0 = *(const short8*)&ks[(nt * 16 + l15) * 72 + quad * 8];
            short8 bk1 = *(const short8*)&ks[(nt * 16 + l15) * 72 + 32 + quad * 8];
            s[nt] = (floatx4){0.f, 0.f, 0.f, 0.f};
            s[nt] = __builtin_amdgcn_mfma_f32_16x16x32_bf16(aq0, bk0, s[nt], 0, 0, 0);
            s[nt] = __builtin_amdgcn_mfma_f32_16x16x32_bf16(aq1, bk1, s[nt], 0, 0, 0);
        }

        // mask + scale + bias + exp (no max, no cross-lane); P -> LDS strip
#pragma unroll
        for (int r = 0; r < 4; ++r) {
            float ps = 0.f;
#pragma unroll
            for (int nt = 0; nt < 4; ++nt) {
                int kh = (int)((hmk >> (nt * 16 + l15)) & 1);
                bool allow = same || ((qh[r] == 0) && (kh == 0));
                float sv = allow ? fmaf(s[nt][r], 0.125f, fb) : -1.0e30f;
                float p = __expf(sv);          // exp(-1e30) = 0 exactly
                ps += p;
                Ps[wave][(quad * 4 + r) * 72 + nt * 16 + l15] = f2bf(p);
            }
            lpart[r] += ps;
        }

        // O strip += P @ V  (wave-private P; V^T from padded LDS)
        short8 ap0 = *(const short8*)&Ps[wave][l15 * 72 + quad * 8];
        short8 ap1 = *(const short8*)&Ps[wave][l15 * 72 + 32 + quad * 8];
#pragma unroll
        for (int dt = 0; dt < 4; ++dt) {
            short8 bv0 = *(const short8*)&vs[(dt * 16 + l15) * 72 + quad * 8];
            short8 bv1 = *(const short8*)&vs[(dt * 16 + l15) * 72 + 32 + quad * 8];
            oacc[dt] = __builtin_amdgcn_mfma_f32_16x16x32_bf16(ap0, bv0, oacc[dt], 0, 0, 0);
            oacc[dt] = __builtin_amdgcn_mfma_f32_16x16x32_bf16(ap1, bv1, oacc[dt], 0, 0, 0);
        }
    }

    // final row-sum reduction across the 16 l15 lanes (once per kernel)
    float linv[4];
#pragma unroll
    for (int r = 0; r < 4; ++r) {
        float ls = lpart[r];
        ls += __shfl_xor(ls, 1);
        ls += __shfl_xor(ls, 2);
        ls += __shfl_xor(ls, 4);
        ls += __shfl_xor(ls, 8);
        linv[r] = 1.0f / ls;
    }

    // epilogue: attnb[row][h*64 + d] bf16
#pragma unroll
    for (int dt = 0; dt < 4; ++dt) {
        int col = h * HDIM + dt * 16 + l15;
#pragma unroll
        for (int r = 0; r < 4; ++r) {
            int row = q0 + wave * 16 + quad * 4 + r;
            attnb[(size_t)row * CDIM + col] = f2bf(oacc[dt][r] * linv[r]);
        }
    }
}

// ---------------------------------------------------------------------------
extern "C" void kernel_launch(void* const* d_in, const int* in_sizes, int n_in,
                              void* d_out, int out_size, void* d_ws, size_t ws_size,
                              hipStream_t stream)
{
    const float* x          = (const float*)d_in[0];
    const int*   frame_ids  = (const int*)d_in[1];
    const int*   is_hub     = (const int*)d_in[2];
    const int*   adj        = (const int*)d_in[3];
    const float* frame_bias = (const float*)d_in[4];
    const float* Wqkv       = (const float*)d_in[5];
    const float* bqkv       = (const float*)d_in[6];
    const float* Wproj      = (const float*)d_in[7];
    const float* bproj      = (const float*)d_in[8];
    float* out = (float*)d_out;

    // workspace layout (ushort units)
    ushort* xb     = (ushort*)d_ws;            // 2048*1024
    ushort* wqkvT  = xb     + 2097152;         // 3072*1024
    ushort* wprojT = wqkvT  + 3145728;         // 1024*1024
    ushort* qkvb   = wprojT + 1048576;         // [2][H][N][D] used
    ushort* vTb    = qkvb   + 6291456;         // 16*64*2048
    ushort* attnb  = vTb    + 2097152;         // 2048*1024
    u64*    hubmask = (u64*)(attnb + 2097152); // 32 x u64

    prep_kernel<<<dim3(3073), dim3(256), 0, stream>>>(
        x, xb, Wqkv, wqkvT, Wproj, wprojT, is_hub, hubmask);

    // QKV: [2048,1024] @ [1024,3072]; Q,K -> qkvb, V -> vTb (fused transpose)
    gemm_bt_kernel<<<dim3(3 * CDIM / 128, NTOK / 128), dim3(256), 0, stream>>>(
        xb, wqkvT, bqkv, qkvb, vTb, NTOK, 3 * CDIM, CDIM, 1);

    attn_tile_kernel<<<dim3(512), dim3(256), 0, stream>>>(
        qkvb, vTb, frame_ids, hubmask, adj, frame_bias, attnb);

    // proj: [2048,1024] @ [1024,1024] -> fp32 d_out
    gemm_bt_kernel<<<dim3(CDIM / 128, NTOK / 128), dim3(256), 0, stream>>>(
        attnb, wprojT, bproj, out, nullptr, NTOK, CDIM, CDIM, 0);
}